// Round 2
// 2024.916 us; speedup vs baseline: 1.1963x; 1.1963x over previous
//
#include <hip/hip_runtime.h>

// Problem dims (fixed per reference)
#define D_DIM 2048
#define I_DIM 1024
#define E_NUM 32
#define TOPK 4
#define T_TOK 4096
#define CAP_R 768           // per-expert capacity (mean 512, sigma ~21 -> +12σ), 6*BM
#define ALPHA 7.0f

// GEMM tiling: 128x64 tiles, BK=32 (shorts), double-buffered LDS, XOR-swizzled
#define BM 128
#define BN 64
#define BK 32

typedef __attribute__((ext_vector_type(8))) short short8;
typedef __attribute__((ext_vector_type(4))) float floatx4;

static __device__ __forceinline__ unsigned short f2bf(float f) {
    union { float f; unsigned u; } v; v.f = f;
    unsigned u = v.u;
    u += 0x7FFFu + ((u >> 16) & 1u);   // RNE
    return (unsigned short)(u >> 16);
}

static __device__ __forceinline__ short8 pack8(const float4 a, const float4 b) {
    short8 r;
    r[0] = (short)f2bf(a.x); r[1] = (short)f2bf(a.y);
    r[2] = (short)f2bf(a.z); r[3] = (short)f2bf(a.w);
    r[4] = (short)f2bf(b.x); r[5] = (short)f2bf(b.y);
    r[6] = (short)f2bf(b.z); r[7] = (short)f2bf(b.w);
    return r;
}

// ---------------------------------------------------------------------------
// Router: logits -> sqrt(softplus) -> top-4 by (score+bias) -> renorm weights
// scatter (token, weight) into per-expert lists. Also emits bf16 copy of x.
// ---------------------------------------------------------------------------
__global__ __launch_bounds__(256) void router_kernel(
    const float* __restrict__ x, const float* __restrict__ rw,
    const float* __restrict__ bias,
    int* __restrict__ counts, int* __restrict__ tlist, float* __restrict__ twgt,
    unsigned short* __restrict__ xbf)
{
    const int t = blockIdx.x;
    const int tid = threadIdx.x;
    const int wave = tid >> 6, lane = tid & 63;
    __shared__ float xs[D_DIM];
    __shared__ float logits[E_NUM];
    const float* xr = x + (long)t * D_DIM;
    unsigned short* xb = xbf + (long)t * D_DIM;
    for (int i = tid; i < D_DIM; i += 256) {
        float v = xr[i];
        xs[i] = v;
        xb[i] = f2bf(v);          // bf16 cache for gateup A-gather
    }
    __syncthreads();
    for (int e = wave; e < E_NUM; e += 4) {
        const float* wr = rw + (long)e * D_DIM;
        float acc = 0.f;
        for (int i = lane; i < D_DIM; i += 64) acc += xs[i] * wr[i];
        for (int off = 32; off > 0; off >>= 1) acc += __shfl_down(acc, off);
        if (lane == 0) logits[e] = acc;
    }
    __syncthreads();
    if (tid == 0) {
        float sc[E_NUM], bsc[E_NUM];
        for (int e2 = 0; e2 < E_NUM; ++e2) {
            float l = logits[e2];
            float sp = (l > 20.f) ? l : log1pf(expf(l));
            float s = sqrtf(sp);
            sc[e2] = s;
            bsc[e2] = s + bias[e2];
        }
        int sel[TOPK]; float ssum = 0.f;
        unsigned usedmask = 0;
        for (int k = 0; k < TOPK; ++k) {
            int best = 0; float bv = -1e30f;
            for (int e2 = 0; e2 < E_NUM; ++e2)
                if (!((usedmask >> e2) & 1u) && bsc[e2] > bv) { bv = bsc[e2]; best = e2; }
            usedmask |= 1u << best;
            sel[k] = best;
            ssum += sc[best];
        }
        float inv = 1.f / (ssum + 1e-20f);
        for (int k = 0; k < TOPK; ++k) {
            int e2 = sel[k];
            int pos = atomicAdd(&counts[e2], 1);
            if (pos < CAP_R) {
                tlist[e2 * CAP_R + pos] = t;
                twgt[e2 * CAP_R + pos] = sc[e2] * inv;
            }
        }
    }
}

// ---------------------------------------------------------------------------
// Fused gate+up GEMM per expert (e==32 -> shared expert, identity token list).
// Double-buffered LDS, 1-ahead register prefetch, single raw barrier per
// K-step (vmcnt NOT drained at the barrier), XOR-swizzled conflict-free LDS.
// ---------------------------------------------------------------------------
__global__ __launch_bounds__(256, 3) void gateup_kernel(
    const unsigned short* __restrict__ xbf,
    const float* __restrict__ gate_w, const float* __restrict__ up_w,
    const float* __restrict__ sgw, const float* __restrict__ suw,
    const int* __restrict__ counts, const int* __restrict__ tlist,
    unsigned short* __restrict__ hbuf)
{
    const int e = blockIdx.z;
    const int mtile = blockIdx.y;
    const int ntile = blockIdx.x;
    const int cnt = (e == E_NUM) ? T_TOK : min(counts[e], CAP_R);
    if (mtile * BM >= cnt) return;

    const float* gw; const float* uw; const int* lst = nullptr; long hbase;
    if (e < E_NUM) {
        gw = gate_w + (long)e * I_DIM * D_DIM;
        uw = up_w   + (long)e * I_DIM * D_DIM;
        lst = tlist + e * CAP_R;
        hbase = (long)e * CAP_R;
    } else {
        gw = sgw; uw = suw; hbase = (long)E_NUM * CAP_R;
    }

    __shared__ __align__(16) short As[2][BM * BK];   // 16 KB
    __shared__ __align__(16) short Bg[2][BN * BK];   // 8 KB
    __shared__ __align__(16) short Bu[2][BN * BK];   // 8 KB

    const int tid = threadIdx.x;
    const int crow = tid >> 2;          // 0..63
    const int cseg = tid & 3;           // 16B segment within a 64B LDS row

    // A gather: 2 chunks (rows crow, crow+64), bf16 source -> single uint4 load
    const unsigned short* aB[2];
    int soffA[2];
    for (int i = 0; i < 2; ++i) {
        int row = crow + i * 64;
        int r = mtile * BM + row;
        int rr = (r < cnt) ? r : (cnt - 1);           // clamp; masked at store
        int tok = (e < E_NUM) ? lst[rr] : rr;
        aB[i] = xbf + (long)tok * D_DIM + cseg * 8;
        soffA[i] = row * BK + ((cseg ^ ((row >> 1) & 3)) << 3);   // XOR swizzle
    }
    // B: 1 chunk (row crow of 64), fp32 source -> 2x float4 + pack
    const long nrow = (long)(ntile * BN + crow);
    const float* gB = gw + nrow * D_DIM + cseg * 8;
    const float* uB = uw + nrow * D_DIM + cseg * 8;
    const int soffB = crow * BK + ((cseg ^ ((crow >> 1) & 3)) << 3);

    const int wave = tid >> 6, lane = tid & 63;
    const int wm = wave >> 1, wn = wave & 1;          // 2x2 wave grid (64x32 tiles)
    const int quad = lane >> 4, l16 = lane & 15;
    int aoff[4], boff[2];
    for (int mi = 0; mi < 4; ++mi) {
        int r = wm * 64 + mi * 16 + l16;
        aoff[mi] = r * BK + ((quad ^ ((r >> 1) & 3)) << 3);
    }
    for (int ni = 0; ni < 2; ++ni) {
        int r = wn * 32 + ni * 16 + l16;
        boff[ni] = r * BK + ((quad ^ ((r >> 1) & 3)) << 3);
    }

    // prologue prefetch (k0 = 0)
    uint4 va[2]; float4 vg[2], vu[2];
    va[0] = *(const uint4*)(aB[0]);
    va[1] = *(const uint4*)(aB[1]);
    vg[0] = *(const float4*)(gB); vg[1] = *(const float4*)(gB + 4);
    vu[0] = *(const float4*)(uB); vu[1] = *(const float4*)(uB + 4);

    floatx4 accg[4][2] = {};
    floatx4 accu[4][2] = {};

    const int NT = D_DIM / BK;
    for (int kt = 0; kt < NT; ++kt) {
        const int buf = kt & 1;
        // store prefetched tile to LDS[buf]
        short* sA = &As[buf][0]; short* sG = &Bg[buf][0]; short* sU = &Bu[buf][0];
        *(uint4*)&sA[soffA[0]] = va[0];
        *(uint4*)&sA[soffA[1]] = va[1];
        *(short8*)&sG[soffB] = pack8(vg[0], vg[1]);
        *(short8*)&sU[soffB] = pack8(vu[0], vu[1]);
        // issue next-tile loads: they ride across the barrier (vmcnt not drained)
        if (kt + 1 < NT) {
            const int k0 = (kt + 1) * BK;
            va[0] = *(const uint4*)(aB[0] + k0);
            va[1] = *(const uint4*)(aB[1] + k0);
            vg[0] = *(const float4*)(gB + k0); vg[1] = *(const float4*)(gB + k0 + 4);
            vu[0] = *(const float4*)(uB + k0); vu[1] = *(const float4*)(uB + k0 + 4);
        }
        asm volatile("s_waitcnt lgkmcnt(0)" ::: "memory");   // drain LDS writes only
        __builtin_amdgcn_s_barrier();
        // compute LDS[buf]
        const short* pA = &As[buf][0];
        const short* pG = &Bg[buf][0];
        const short* pU = &Bu[buf][0];
        short8 af[4];
        for (int mi = 0; mi < 4; ++mi) af[mi] = *(const short8*)&pA[aoff[mi]];
        for (int ni = 0; ni < 2; ++ni) {
            short8 g8 = *(const short8*)&pG[boff[ni]];
            short8 u8 = *(const short8*)&pU[boff[ni]];
            for (int mi = 0; mi < 4; ++mi) {
                accg[mi][ni] = __builtin_amdgcn_mfma_f32_16x16x32_bf16(af[mi], g8, accg[mi][ni], 0, 0, 0);
                accu[mi][ni] = __builtin_amdgcn_mfma_f32_16x16x32_bf16(af[mi], u8, accu[mi][ni], 0, 0, 0);
            }
        }
        // single barrier per K-step is safe: store(kt+2) into buf happens after
        // barrier(kt+1), and all LDS reads of compute(kt) are drained (lgkmcnt(0))
        // before any wave crosses barrier(kt+1).
    }

    // epilogue: clamp, silu(g)*u, bf16 store to h scratch
    for (int mi = 0; mi < 4; ++mi)
    for (int r4 = 0; r4 < 4; ++r4) {
        int lrow = wm * 64 + mi * 16 + quad * 4 + r4;
        int grow = mtile * BM + lrow;
        if (grow >= cnt) continue;
        unsigned short* hrow = hbuf + (hbase + grow) * I_DIM + ntile * BN + wn * 32 + l16;
        for (int ni = 0; ni < 2; ++ni) {
            float g = accg[mi][ni][r4];
            float u = accu[mi][ni][r4];
            g = fminf(fmaxf(g, -ALPHA), ALPHA);
            u = fminf(fmaxf(u, -ALPHA), ALPHA);
            float h = g / (1.f + expf(-g)) * u;
            hrow[ni * 16] = f2bf(h);
        }
    }
}

// ---------------------------------------------------------------------------
// Down GEMM per expert: C = h_e @ Wd^T ; out[token] += p * C  (atomic fp32)
// Same pipelined structure; A (hbuf) is already bf16 -> direct uint4 loads.
// ---------------------------------------------------------------------------
__global__ __launch_bounds__(256, 4) void down_kernel(
    const unsigned short* __restrict__ hbuf,
    const float* __restrict__ down_w, const float* __restrict__ sdw,
    const int* __restrict__ counts, const int* __restrict__ tlist,
    const float* __restrict__ twgt,
    float* __restrict__ out)
{
    const int e = blockIdx.z;
    const int mtile = blockIdx.y;
    const int ntile = blockIdx.x;      // D/64 = 32
    const int cnt = (e == E_NUM) ? T_TOK : min(counts[e], CAP_R);
    if (mtile * BM >= cnt) return;

    const float* dw = (e < E_NUM) ? down_w + (long)e * D_DIM * I_DIM : sdw;
    const long hbase = (e < E_NUM) ? (long)e * CAP_R : (long)E_NUM * CAP_R;
    const int* lst = tlist + (e < E_NUM ? e : 0) * CAP_R;
    const float* wgt = twgt + (e < E_NUM ? e : 0) * CAP_R;

    __shared__ __align__(16) short As[2][BM * BK];   // 16 KB
    __shared__ __align__(16) short Bs[2][BN * BK];   // 8 KB

    const int tid = threadIdx.x;
    const int crow = tid >> 2;
    const int cseg = tid & 3;

    const unsigned short* aB[2]; int soffA[2];
    for (int i = 0; i < 2; ++i) {
        int row = crow + i * 64;
        aB[i] = hbuf + (hbase + mtile * BM + row) * I_DIM + cseg * 8;
        soffA[i] = row * BK + ((cseg ^ ((row >> 1) & 3)) << 3);
    }
    const float* bB = dw + (long)(ntile * BN + crow) * I_DIM + cseg * 8;
    const int soffB = crow * BK + ((cseg ^ ((crow >> 1) & 3)) << 3);

    const int wave = tid >> 6, lane = tid & 63;
    const int wm = wave >> 1, wn = wave & 1;
    const int quad = lane >> 4, l16 = lane & 15;
    int aoff[4], boff[2];
    for (int mi = 0; mi < 4; ++mi) {
        int r = wm * 64 + mi * 16 + l16;
        aoff[mi] = r * BK + ((quad ^ ((r >> 1) & 3)) << 3);
    }
    for (int ni = 0; ni < 2; ++ni) {
        int r = wn * 32 + ni * 16 + l16;
        boff[ni] = r * BK + ((quad ^ ((r >> 1) & 3)) << 3);
    }

    uint4 va[2]; float4 vb[2];
    va[0] = *(const uint4*)(aB[0]);
    va[1] = *(const uint4*)(aB[1]);
    vb[0] = *(const float4*)(bB); vb[1] = *(const float4*)(bB + 4);

    floatx4 acc[4][2] = {};

    const int NT = I_DIM / BK;
    for (int kt = 0; kt < NT; ++kt) {
        const int buf = kt & 1;
        short* sA = &As[buf][0]; short* sB = &Bs[buf][0];
        *(uint4*)&sA[soffA[0]] = va[0];
        *(uint4*)&sA[soffA[1]] = va[1];
        *(short8*)&sB[soffB] = pack8(vb[0], vb[1]);
        if (kt + 1 < NT) {
            const int k0 = (kt + 1) * BK;
            va[0] = *(const uint4*)(aB[0] + k0);
            va[1] = *(const uint4*)(aB[1] + k0);
            vb[0] = *(const float4*)(bB + k0); vb[1] = *(const float4*)(bB + k0 + 4);
        }
        asm volatile("s_waitcnt lgkmcnt(0)" ::: "memory");
        __builtin_amdgcn_s_barrier();
        const short* pA = &As[buf][0];
        const short* pB = &Bs[buf][0];
        short8 af[4];
        for (int mi = 0; mi < 4; ++mi) af[mi] = *(const short8*)&pA[aoff[mi]];
        for (int ni = 0; ni < 2; ++ni) {
            short8 b8 = *(const short8*)&pB[boff[ni]];
            for (int mi = 0; mi < 4; ++mi)
                acc[mi][ni] = __builtin_amdgcn_mfma_f32_16x16x32_bf16(af[mi], b8, acc[mi][ni], 0, 0, 0);
        }
    }

    for (int mi = 0; mi < 4; ++mi)
    for (int r4 = 0; r4 < 4; ++r4) {
        int lrow = wm * 64 + mi * 16 + quad * 4 + r4;
        int grow = mtile * BM + lrow;
        if (grow >= cnt) continue;
        int tok; float w;
        if (e < E_NUM) { tok = lst[grow]; w = wgt[grow]; }
        else           { tok = grow;     w = 1.f; }
        float* orow = out + (long)tok * D_DIM + ntile * BN + wn * 32 + l16;
        for (int ni = 0; ni < 2; ++ni)
            atomicAdd(orow + ni * 16, w * acc[mi][ni][r4]);
    }
}

// ---------------------------------------------------------------------------
extern "C" void kernel_launch(void* const* d_in, const int* in_sizes, int n_in,
                              void* d_out, int out_size, void* d_ws, size_t ws_size,
                              hipStream_t stream) {
    const float* hidden   = (const float*)d_in[0];
    const float* router_w = (const float*)d_in[1];
    const float* ebias    = (const float*)d_in[2];
    const float* gate_w   = (const float*)d_in[3];
    const float* up_w     = (const float*)d_in[4];
    const float* down_w   = (const float*)d_in[5];
    const float* sgw      = (const float*)d_in[6];
    const float* suw      = (const float*)d_in[7];
    const float* sdw      = (const float*)d_in[8];
    float* out = (float*)d_out;

    // Workspace layout (total ~72.18 MiB, <= previous proven 72.25 MiB):
    //   counts: 256 B
    //   tlist : 32*768*4  =  96 KiB
    //   twgt  : 32*768*4  =  96 KiB
    //   xbf   : 4096*2048*2 = 16 MiB   (bf16 hidden cache)
    //   hbuf  : (32*768+4096)*1024*2 = 56 MiB
    char* ws = (char*)d_ws;
    int*   counts = (int*)ws;
    int*   tlist  = (int*)(ws + 256);
    float* twgt   = (float*)(ws + 256 + E_NUM * CAP_R * 4);
    unsigned short* xbf  = (unsigned short*)(ws + 256 + 2 * E_NUM * CAP_R * 4);
    unsigned short* hbuf = xbf + (size_t)T_TOK * D_DIM;

    hipMemsetAsync(counts, 0, 256, stream);
    hipMemsetAsync(out, 0, (size_t)out_size * sizeof(float), stream);

    router_kernel<<<T_TOK, 256, 0, stream>>>(hidden, router_w, ebias,
                                             counts, tlist, twgt, xbf);
    gateup_kernel<<<dim3(I_DIM / BN, T_TOK / BM, E_NUM + 1), 256, 0, stream>>>(
        xbf, gate_w, up_w, sgw, suw, counts, tlist, hbuf);
    down_kernel<<<dim3(D_DIM / BN, T_TOK / BM, E_NUM + 1), 256, 0, stream>>>(
        hbuf, down_w, sdw, counts, tlist, twgt, out);
}